// Round 7
// baseline (650.937 us; speedup 1.0000x reference)
//
#include <hip/hip_runtime.h>
#include <hip/hip_cooperative_groups.h>
#include <hip/hip_bf16.h>
#include <math.h>

typedef __hip_bfloat16 bf16;
typedef __attribute__((ext_vector_type(8))) short frag8;
typedef __attribute__((ext_vector_type(4))) float f32x4;
typedef __attribute__((ext_vector_type(16))) float f32x16;
typedef __attribute__((ext_vector_type(2))) unsigned int u32x2;
typedef __attribute__((ext_vector_type(4))) unsigned int u32x4;

#define HW  1296
#define CH  128
#define TT  1327104   // 8 * 1296 * 128

__device__ __forceinline__ float b2f(bf16 v) { return __bfloat162float(v); }
__device__ __forceinline__ float bits2f(unsigned short u) {
    return __uint_as_float(((unsigned)u) << 16);
}
__device__ __forceinline__ float frcp(float x) { return __builtin_amdgcn_rcpf(x); }
__device__ __forceinline__ float fsigm(float x) { return frcp(1.0f + __expf(-x)); }
__device__ __forceinline__ float ftanh(float x) {
    float xc = fminf(15.0f, fmaxf(-15.0f, x));
    float e = __expf(2.0f * xc);
    return (e - 1.0f) * frcp(e + 1.0f);
}
// round-half-up f32->bf16 pair pack: 2 adds + 1 v_perm
__device__ __forceinline__ int packrh(float a, float b) {
    unsigned ua = __float_as_uint(a) + 0x8000u;
    unsigned ub = __float_as_uint(b) + 0x8000u;
    return (int)__builtin_amdgcn_perm(ub, ua, 0x07060302);
}
__device__ __forceinline__ int2 pack4(float a, float b, float c, float d) {
    int2 r; r.x = packrh(a, b); r.y = packrh(c, d); return r;
}
// packed RNE f32 pair -> bf16x2 in one VALU op
__device__ __forceinline__ unsigned cvtpk(float a, float b) {
    unsigned r;
    asm("v_cvt_pk_bf16_f32 %0, %1, %2" : "=v"(r) : "v"(a), "v"(b));
    return r;
}

// inline wave-uniform dtype detection (256 probe elems of w_in)
__device__ __forceinline__ int detect_f32(const void* w) {
    const short4* p = (const short4*)w;
    short4 v = p[threadIdx.x & 63];
    int bad = 0;
    #pragma unroll
    for (int j = 0; j < 4; ++j) {
        float f = bits2f(((const unsigned short*)&v)[j]);
        if (!(fabsf(f) <= 100.0f)) bad = 1;   // catches NaN/Inf too
    }
    return __any(bad) ? 1 : 0;
}

// all pointers bundled so every kernel/phase shares one signature
struct MP {
    const void *x, *w_in, *w_conv, *wq, *wk, *wv, *w_i, *w_g, *w_o, *w_out;
    const void *b_in, *b_conv, *b_i, *b_g, *b_o, *b_out;
    bf16* Wst; float* Bst;
    bf16 *XT, *Zb, *Qb, *Kb, *Vb, *Ab;
    void* out;
};

// ---------------- phase 0: weight prep ----------------
// Wst (bf16): w_in[128o][128i]@0 | wconvT[9tap][128o][128r]@16384 |
//   wqkv[384o][128i]@163840 | wg[3][128o][256k]@212992 | wout[128o][128i]@311296
// Bst f32[768]: in@0 conv@128 i@256 g@384 o@512 out@640
// wq rows pre-scaled by log2(e) so attention uses exp2 directly.
__device__ __forceinline__ void dev_prep(const MP& p, int idx, int f) {
    if (idx < 327680) {
        const void* src; int si;
        if (idx < 16384)       { src = p.w_in; si = idx; }
        else if (idx < 163840) { int j = idx - 16384; int tap = j >> 14, rem = j & 16383;
                                 int o = rem >> 7, r = rem & 127;
                                 src = p.w_conv; si = o * 2304 + r * 9 + tap; }
        else if (idx < 212992) { int j = idx - 163840; int o = j >> 7, i = j & 127;
                                 int ws_ = o >> 7;
                                 src = ws_ == 0 ? p.wq : ws_ == 1 ? p.wk : p.wv;
                                 si = (o & 127) * 128 + i; }
        else if (idx < 311296) { int j = idx - 212992; int g = j >> 15, rem = j & 32767;
                                 int o = rem >> 8, k = rem & 255;
                                 src = g == 0 ? p.w_i : g == 1 ? p.w_g : p.w_o;
                                 si = o * 256 + k; }
        else                   { int j = idx - 311296; int o = j >> 7, i = j & 127;
                                 src = p.w_out; si = o * 128 + i; }
        float v = f ? ((const float*)src)[si] : b2f(((const bf16*)src)[si]);
        if (idx >= 163840 && idx < 180224) v *= 1.4426950408889634f;  // wq * log2(e)
        p.Wst[idx] = __float2bfloat16(v);
    } else if (idx < 327680 + 768) {
        int j = idx - 327680; int b = j >> 7, e = j & 127;
        const void* src = b == 0 ? p.b_in : b == 1 ? p.b_conv : b == 2 ? p.b_i
                        : b == 3 ? p.b_g : b == 4 ? p.b_o : p.b_out;
        p.Bst[j] = f ? ((const float*)src)[e] : b2f(((const bf16*)src)[e]);
    }
}

// ---------------- phase 1: fused transpose + in-GEMM + tanh (32p x 32o tile) ----------------
__device__ __forceinline__ void dev_inm(const MP& p, int f, int n, int py, int oz,
                                        short (*Xl)[132]) {
    const int tid = threadIdx.x, wave = tid >> 6, lane = tid & 63;
    const int quad = lane >> 4, l16 = lane & 15;
    const int pbase = py * 32;
    const int obase = oz * 32 + (wave & 1) * 16;
    const int pstrip = (wave >> 1) * 16;
    const bf16* Wm = p.Wst;
    const float* bias = p.Bst;

    // weight frags are LDS-independent: issue up front (overlap staging+barrier)
    frag8 WF[4];
    #pragma unroll
    for (int kc = 0; kc < 4; ++kc)
        WF[kc] = *(const frag8*)&Wm[(obase + l16) * CH + kc * 32 + quad * 8];

    #pragma unroll
    for (int rep = 0; rep < 4; ++rep) {
        int u = tid + rep * 256;
        int i = u >> 3;
        int p4 = (u & 7) * 4;
        int pp = pbase + p4;
        short4 s = {0, 0, 0, 0};
        if (pp < HW) {
            size_t gi = (size_t)n * CH * HW + (size_t)i * HW + pp;
            if (f) {
                float4 fv = *(const float4*)((const float*)p.x + gi);
                int2 pk = pack4(fv.x, fv.y, fv.z, fv.w);
                s = *(short4*)&pk;
            } else {
                s = *(const short4*)((const bf16*)p.x + gi);
            }
        }
        Xl[p4 + 0][i] = s.x; Xl[p4 + 1][i] = s.y;
        Xl[p4 + 2][i] = s.z; Xl[p4 + 3][i] = s.w;
    }
    __syncthreads();

    const int pl = pstrip + l16;
    f32x4 acc = {0.f, 0.f, 0.f, 0.f};
    #pragma unroll
    for (int kc = 0; kc < 4; ++kc) {
        int k = kc * 32 + quad * 8;
        short4 b0 = *(const short4*)&Xl[pl][k];
        short4 b1 = *(const short4*)&Xl[pl][k + 4];
        frag8 bf = {b0.x, b0.y, b0.z, b0.w, b1.x, b1.y, b1.z, b1.w};
        acc = __builtin_amdgcn_mfma_f32_16x16x32_bf16(WF[kc], bf, acc, 0, 0, 0);
    }

    int pp = pbase + pstrip + l16;
    if (pp < HW) {
        int og = obase + quad * 4;
        int2 pk = pack4(ftanh(acc[0] + bias[og + 0]), ftanh(acc[1] + bias[og + 1]),
                        ftanh(acc[2] + bias[og + 2]), ftanh(acc[3] + bias[og + 3]));
        *(int2*)((short*)p.XT + ((size_t)n * HW + pp) * CH + og) = pk;
    }
    __syncthreads();   // protect Xl for tile-loop reuse
}

// ---------------- phase 2: 3x3 conv GEMM (64p x 32o tile, 2-deep tap pipeline) ----------------
__device__ __forceinline__ void dev_conv(const MP& p, int n, int py, int oz) {
    const int tid = threadIdx.x, wave = tid >> 6, lane = tid & 63;
    const int quad = lane >> 4, l16 = lane & 15;
    const int ostrip = wave & 1, pstrip = wave >> 1;
    const int obase = oz * 32 + ostrip * 16;
    const int pbase = py * 64 + pstrip * 32;
    const bf16* Wm = p.Wst + 16384;
    const float* bias = p.Bst + 128;
    const bf16* actn = p.XT + (size_t)n * HW * CH;

    const int p1 = pbase + l16, p2 = pbase + 16 + l16;
    const bool p1ok = p1 < HW, p2ok = p2 < HW;
    const int h1 = p1 / 36, w1 = p1 - h1 * 36;
    const int h2 = p2 / 36, w2 = p2 - h2 * 36;

    frag8 zf = {0, 0, 0, 0, 0, 0, 0, 0};
    f32x4 acc[2];
    acc[0] = (f32x4){0.f, 0.f, 0.f, 0.f};
    acc[1] = (f32x4){0.f, 0.f, 0.f, 0.f};

    frag8 A1[2][4], A2[2][4], WT[2][4];

    #define LOADTAP(TAP, BUF)                                                        \
    {                                                                                \
        const int dy = (TAP) / 3 - 1, dx = (TAP) - ((TAP) / 3) * 3 - 1;              \
        const bool ok1 = p1ok && (unsigned)(h1 + dy) < 36u && (unsigned)(w1 + dx) < 36u; \
        const bool ok2 = p2ok && (unsigned)(h2 + dy) < 36u && (unsigned)(w2 + dx) < 36u; \
        const int sh = dy * 36 + dx;                                                 \
        const bf16* a1 = actn + (size_t)(p1 + sh) * CH + quad * 8;                   \
        const bf16* a2 = actn + (size_t)(p2 + sh) * CH + quad * 8;                   \
        const bf16* wp = Wm + (TAP) * 16384 + (obase + l16) * CH + quad * 8;         \
        _Pragma("unroll")                                                            \
        for (int kc = 0; kc < 4; ++kc) {                                             \
            A1[BUF][kc] = ok1 ? *(const frag8*)&a1[kc * 32] : zf;                    \
            A2[BUF][kc] = ok2 ? *(const frag8*)&a2[kc * 32] : zf;                    \
            WT[BUF][kc] = *(const frag8*)&wp[kc * 32];                               \
        }                                                                            \
    }

    LOADTAP(0, 0);
    #pragma unroll
    for (int tap = 0; tap < 9; ++tap) {
        const int cur = tap & 1;
        if (tap < 8) LOADTAP(tap + 1, cur ^ 1);
        #pragma unroll
        for (int kc = 0; kc < 4; ++kc) {
            acc[0] = __builtin_amdgcn_mfma_f32_16x16x32_bf16(WT[cur][kc], A1[cur][kc], acc[0], 0, 0, 0);
            acc[1] = __builtin_amdgcn_mfma_f32_16x16x32_bf16(WT[cur][kc], A2[cur][kc], acc[1], 0, 0, 0);
        }
    }
    #undef LOADTAP

    const int og = obase + quad * 4;
    #pragma unroll
    for (int pt = 0; pt < 2; ++pt) {
        int pp = pbase + pt * 16 + l16;
        if (pp >= HW) continue;
        size_t rowoff = ((size_t)n * HW + pp) * CH;
        int2 pk = pack4(acc[pt][0] + bias[og + 0], acc[pt][1] + bias[og + 1],
                        acc[pt][2] + bias[og + 2], acc[pt][3] + bias[og + 3]);
        *(int2*)((short*)p.Zb + rowoff + og) = pk;
    }
}

// ---------------- phase 3: QKV GEMM (64o x 64p tile, all frags up front) ----------------
__device__ __forceinline__ void dev_qkv(const MP& p, int n, int py, int oz) {
    const int tid = threadIdx.x, wave = tid >> 6, lane = tid & 63;
    const int quad = lane >> 4, l16 = lane & 15;
    const int ostrip = wave & 1, pstrip = wave >> 1;
    const int obase = oz * 64 + ostrip * 32;
    const int pbase = py * 64 + pstrip * 32;
    const bf16* Wm = p.Wst + 163840;
    const bf16* actn = p.Zb + (size_t)n * HW * CH;
    const bool vtile = (oz >= 4);   // block-uniform

    const int p1 = pbase + l16, p2 = pbase + 16 + l16;
    const bool p1ok = p1 < HW, p2ok = p2 < HW;

    frag8 zf = {0, 0, 0, 0, 0, 0, 0, 0};
    frag8 B1[4], B2[4], W0a[4], W1a[4];
    #pragma unroll
    for (int kc = 0; kc < 4; ++kc) {
        int ko = kc * 32 + quad * 8;
        B1[kc] = p1ok ? *(const frag8*)&actn[(size_t)p1 * CH + ko] : zf;
        B2[kc] = p2ok ? *(const frag8*)&actn[(size_t)p2 * CH + ko] : zf;
        W0a[kc] = *(const frag8*)&Wm[(size_t)(obase + l16) * CH + ko];
        W1a[kc] = *(const frag8*)&Wm[(size_t)(obase + 16 + l16) * CH + ko];
    }

    f32x4 acc[2][2];   // [of][pt]
    #pragma unroll
    for (int of = 0; of < 2; ++of) {
        acc[of][0] = (f32x4){0.f, 0.f, 0.f, 0.f};
        acc[of][1] = (f32x4){0.f, 0.f, 0.f, 0.f};
    }

    #pragma unroll
    for (int kc = 0; kc < 4; ++kc) {
        if (vtile) {
            acc[0][0] = __builtin_amdgcn_mfma_f32_16x16x32_bf16(B1[kc], W0a[kc], acc[0][0], 0, 0, 0);
            acc[0][1] = __builtin_amdgcn_mfma_f32_16x16x32_bf16(B2[kc], W0a[kc], acc[0][1], 0, 0, 0);
            acc[1][0] = __builtin_amdgcn_mfma_f32_16x16x32_bf16(B1[kc], W1a[kc], acc[1][0], 0, 0, 0);
            acc[1][1] = __builtin_amdgcn_mfma_f32_16x16x32_bf16(B2[kc], W1a[kc], acc[1][1], 0, 0, 0);
        } else {
            acc[0][0] = __builtin_amdgcn_mfma_f32_16x16x32_bf16(W0a[kc], B1[kc], acc[0][0], 0, 0, 0);
            acc[0][1] = __builtin_amdgcn_mfma_f32_16x16x32_bf16(W0a[kc], B2[kc], acc[0][1], 0, 0, 0);
            acc[1][0] = __builtin_amdgcn_mfma_f32_16x16x32_bf16(W1a[kc], B1[kc], acc[1][0], 0, 0, 0);
            acc[1][1] = __builtin_amdgcn_mfma_f32_16x16x32_bf16(W1a[kc], B2[kc], acc[1][1], 0, 0, 0);
        }
    }

    if (vtile) {
        #pragma unroll
        for (int of = 0; of < 2; ++of) {
            int ov = obase + of * 16 - 256 + l16;
            #pragma unroll
            for (int pt = 0; pt < 2; ++pt) {
                int p4 = pbase + pt * 16 + quad * 4;
                if (p4 >= HW) continue;
                int2 pk = pack4(acc[of][pt][0], acc[of][pt][1], acc[of][pt][2], acc[of][pt][3]);
                *(int2*)((short*)p.Vb + ((size_t)n * CH + ov) * HW + p4) = pk;
            }
        }
        return;
    }
    #pragma unroll
    for (int of = 0; of < 2; ++of) {
        int og = obase + of * 16 + quad * 4;
        int which = og >> 7, ol = og & 127;
        bf16* dst = which == 0 ? p.Qb : p.Kb;
        #pragma unroll
        for (int pt = 0; pt < 2; ++pt) {
            int pp = pbase + pt * 16 + l16;
            if (pp >= HW) continue;
            size_t di = (((size_t)n * 8 + (ol >> 4)) * HW + pp) * 16 + (ol & 15);
            int2 pk = pack4(acc[of][pt][0], acc[of][pt][1], acc[of][pt][2], acc[of][pt][3]);
            *(int2*)((short*)dst + di) = pk;
        }
    }
}

// ---------------- phase 4: flash attention (4 waves: 2 qw x 2 dq), 32x32x16 ----------------
// S layout (m74/m101): col=q=lane&31, row=d_local=(r&3)+8*(r>>2)+4*(lane>>5).
// lsum free: V A-operand row c==16 all-ones -> Oacc[8] = sum_d P[d][q].
// Next chunk's QK^T issues before current exp2/pack; K prefetched 2 deep.
__device__ __forceinline__ void dev_attn(const MP& p, int n, int qt, int head,
                                         float (*Lc)[9][64]) {
    const int tid = threadIdx.x;
    const int w = tid >> 6, lane = tid & 63;
    const int l32 = lane & 31, hi = lane >> 5;
    const int qw = w & 1, dq = w >> 1;
    const int qb = qt * 64 + qw * 32;
    const int qtok = qb + l32;

    const short* Qh = (const short*)p.Qb + ((size_t)(n * 8 + head)) * HW * 16;
    const short* Kh = (const short*)p.Kb + ((size_t)(n * 8 + head)) * HW * 16;
    const short* Vh = (const short*)p.Vb + ((size_t)n * CH + head * 16) * HW;

    frag8 qf = {0, 0, 0, 0, 0, 0, 0, 0};
    if (qtok < HW) qf = *(const frag8*)&Qh[(size_t)qtok * 16 + hi * 8];

    const short one = (short)0x3F80;
    const frag8 vones = {one, one, one, one, one, one, one, one};
    const frag8 vzero = {0, 0, 0, 0, 0, 0, 0, 0};
    const frag8 vfill = (l32 == 16) ? vones : vzero;
    const bool vload = l32 < 16;
    const short* Vrow = Vh + (size_t)(vload ? l32 : 0) * HW;

    const f32x16 zero16 = {};
    f32x16 Oacc = {};

    auto KLD = [&](int dd) -> frag8 {
        return *(const frag8*)&Kh[(size_t)(dd + l32) * 16 + hi * 8];
    };
    auto VLD = [&](int dd) -> frag8 {
        return vload ? *(const frag8*)&Vrow[dd + hi * 8] : vfill;
    };

    const int c0 = dq ? 20 : 0;
    frag8 kf  = KLD(c0 * 32);
    frag8 kf2 = KLD(c0 * 32 + 32);
    frag8 va  = VLD(c0 * 32);
    frag8 vb  = VLD(c0 * 32 + 16);
    f32x16 S = __builtin_amdgcn_mfma_f32_32x32x16_bf16(kf, qf, zero16, 0, 0, 0);

    for (int it = 0; it < 20; ++it) {
        const int d0 = (c0 + it) * 32;
        frag8 kn  = KLD(d0 + 64);
        frag8 van = VLD(d0 + 32);
        frag8 vbn = VLD(d0 + 48);
        f32x16 Sn = __builtin_amdgcn_mfma_f32_32x32x16_bf16(kf2, qf, zero16, 0, 0, 0);

        float pe[16];
        #pragma unroll
        for (int r = 0; r < 16; ++r) pe[r] = __builtin_amdgcn_exp2f(S[r]);

        #pragma unroll
        for (int hh = 0; hh < 2; ++hh) {
            unsigned P0 = cvtpk(pe[hh * 8 + 0], pe[hh * 8 + 1]);
            unsigned P1 = cvtpk(pe[hh * 8 + 2], pe[hh * 8 + 3]);
            unsigned P2 = cvtpk(pe[hh * 8 + 4], pe[hh * 8 + 5]);
            unsigned P3 = cvtpk(pe[hh * 8 + 6], pe[hh * 8 + 7]);
            u32x2 s02 = __builtin_amdgcn_permlane32_swap(P0, P2, false, false);
            u32x2 s13 = __builtin_amdgcn_permlane32_swap(P1, P3, false, false);
            u32x4 bw = {s02[0], s13[0], s02[1], s13[1]};
            frag8 pf = __builtin_bit_cast(frag8, bw);
            Oacc = __builtin_amdgcn_mfma_f32_32x32x16_bf16(hh ? vb : va, pf, Oacc, 0, 0, 0);
        }
        kf2 = kn; va = van; vb = vbn; S = Sn;
    }

    if (dq) {
        // tail chunk 40: d 1280..1295 = S rows 0..7, V in va
        float pe[8];
        #pragma unroll
        for (int r = 0; r < 8; ++r) pe[r] = __builtin_amdgcn_exp2f(S[r]);
        unsigned P0 = cvtpk(pe[0], pe[1]);
        unsigned P1 = cvtpk(pe[2], pe[3]);
        unsigned P2 = cvtpk(pe[4], pe[5]);
        unsigned P3 = cvtpk(pe[6], pe[7]);
        u32x2 s02 = __builtin_amdgcn_permlane32_swap(P0, P2, false, false);
        u32x2 s13 = __builtin_amdgcn_permlane32_swap(P1, P3, false, false);
        u32x4 bw = {s02[0], s13[0], s02[1], s13[1]};
        frag8 pf = __builtin_bit_cast(frag8, bw);
        Oacc = __builtin_amdgcn_mfma_f32_32x32x16_bf16(va, pf, Oacc, 0, 0, 0);
        #pragma unroll
        for (int r = 0; r < 8; ++r) Lc[qw][r][lane] = Oacc[r];
        Lc[qw][8][lane] = Oacc[8];
    }
    __syncthreads();
    if (dq == 0) {
        #pragma unroll
        for (int r = 0; r < 8; ++r) Oacc[r] += Lc[qw][r][lane];
        float lsum = Oacc[8] + Lc[qw][8][lane];
        u32x2 lb = __builtin_amdgcn_permlane32_swap(__float_as_uint(lsum),
                                                    __float_as_uint(lsum), false, false);
        float inv = frcp(__uint_as_float(lb[0]));
        if (qtok < HW) {
            short* An = (short*)p.Ab + ((size_t)n * HW + qtok) * CH + head * 16;
            int2 pk0 = pack4(Oacc[0] * inv, Oacc[1] * inv, Oacc[2] * inv, Oacc[3] * inv);
            int2 pk1 = pack4(Oacc[4] * inv, Oacc[5] * inv, Oacc[6] * inv, Oacc[7] * inv);
            *(int2*)&An[hi * 4] = pk0;
            *(int2*)&An[8 + hi * 4] = pk1;
        }
    }
    __syncthreads();   // protect Lc for tile-loop reuse
}

// ---------------- phase 5: gates GEMM + LSTM cell + fused out-projection (16p tile) ----------------
__device__ __forceinline__ void dev_cell(const MP& p, int f32f, int n, int py,
                                         short (*Hl)[136]) {
    const int tid = threadIdx.x, w = tid >> 6, lane = tid & 63;
    const int quad = lane >> 4, l16 = lane & 15;
    const int pbase = py * 16;
    const bf16* zn = p.Zb + (size_t)n * HW * CH;
    const bf16* an = p.Ab + (size_t)n * HW * CH;
    const bf16* Wg = p.Wst + 212992;
    const float* bg = p.Bst + 256;
    const bf16* Wo = p.Wst + 311296;
    const float* bo = p.Bst + 640;

    const int obase = w * 32;
    const int p1 = pbase + l16;   // always < HW (81*16 == 1296)

    f32x4 acc[3][2];
    #pragma unroll
    for (int g = 0; g < 3; ++g) {
        acc[g][0] = (f32x4){0.f, 0.f, 0.f, 0.f};
        acc[g][1] = (f32x4){0.f, 0.f, 0.f, 0.f};
    }

    frag8 GB[2];
    frag8 GW[2][6];

    #define LOADG(KC, BUF)                                                           \
    {                                                                                \
        const bf16* src = ((KC) >= 4) ? an : zn;                                     \
        const int ko = ((KC) & 3) * 32 + quad * 8;                                   \
        GB[BUF] = *(const frag8*)&src[(size_t)p1 * CH + ko];                         \
        _Pragma("unroll")                                                            \
        for (int g = 0; g < 3; ++g) {                                                \
            _Pragma("unroll")                                                        \
            for (int of = 0; of < 2; ++of)                                           \
                GW[BUF][g * 2 + of] = *(const frag8*)&Wg[g * 32768 +                 \
                    (obase + of * 16 + l16) * 256 + (KC) * 32 + quad * 8];           \
        }                                                                            \
    }

    LOADG(0, 0);
    #pragma unroll
    for (int kc = 0; kc < 8; ++kc) {
        const int cur = kc & 1;
        if (kc < 7) LOADG(kc + 1, cur ^ 1);
        #pragma unroll
        for (int g = 0; g < 3; ++g) {
            #pragma unroll
            for (int of = 0; of < 2; ++of)
                acc[g][of] = __builtin_amdgcn_mfma_f32_16x16x32_bf16(
                    GW[cur][g * 2 + of], GB[cur], acc[g][of], 0, 0, 0);
        }
    }
    #undef LOADG

    // cell nonlinearity -> LDS h tile (C layout: row o = quad*4+r, col p = l16)
    #pragma unroll
    for (int of = 0; of < 2; ++of) {
        int og = obase + of * 16 + quad * 4;
        float hv[4];
        #pragma unroll
        for (int r = 0; r < 4; ++r) {
            int o = og + r;
            float iv = fsigm(acc[0][of][r] + bg[o]);
            float gv = ftanh(acc[1][of][r] + bg[128 + o]);
            float ov = fsigm(acc[2][of][r] + bg[256 + o]);
            hv[r] = ov * ftanh(iv * gv);
        }
        *(int2*)&Hl[l16][og] = pack4(hv[0], hv[1], hv[2], hv[3]);
    }

    // out-phase weight frags: LDS-independent, issue before the barrier
    frag8 OW[2][4];
    #pragma unroll
    for (int of = 0; of < 2; ++of)
        #pragma unroll
        for (int kc = 0; kc < 4; ++kc)
            OW[of][kc] = *(const frag8*)&Wo[(size_t)(obase + of * 16 + l16) * CH
                                            + kc * 32 + quad * 8];
    __syncthreads();

    f32x4 oc[2];
    oc[0] = (f32x4){0.f, 0.f, 0.f, 0.f};
    oc[1] = (f32x4){0.f, 0.f, 0.f, 0.f};
    #pragma unroll
    for (int kc = 0; kc < 4; ++kc) {
        int k = kc * 32 + quad * 8;
        short4 h0 = *(const short4*)&Hl[l16][k];
        short4 h1 = *(const short4*)&Hl[l16][k + 4];
        frag8 af = {h0.x, h0.y, h0.z, h0.w, h1.x, h1.y, h1.z, h1.w};
        #pragma unroll
        for (int of = 0; of < 2; ++of)
            oc[of] = __builtin_amdgcn_mfma_f32_16x16x32_bf16(af, OW[of][kc], oc[of], 0, 0, 0);
    }
    int p4 = pbase + quad * 4;
    #pragma unroll
    for (int of = 0; of < 2; ++of) {
        int o = obase + of * 16 + l16;
        float bv = bo[o];
        size_t di = ((size_t)n * CH + o) * HW + p4;
        if (f32f) {
            float4 fv = {oc[of][0] + bv, oc[of][1] + bv, oc[of][2] + bv, oc[of][3] + bv};
            *(float4*)&((float*)p.out)[di] = fv;
        } else {
            int2 pk = pack4(oc[of][0] + bv, oc[of][1] + bv, oc[of][2] + bv, oc[of][3] + bv);
            *(int2*)&((short*)p.out)[di] = pk;
        }
    }
    __syncthreads();   // protect Hl for tile-loop reuse
}

// ================= persistent cooperative mega-kernel =================
// grid 768 = 3 blocks/CU: guaranteed co-resident (LDS 17.4KB/block -> 52KB/CU,
// VGPR cap 168 via launch_bounds). 5 grid syncs replace 5 launch+drain
// boundaries. Tile->block stride 768 (≡0 mod 8) preserves n->XCD locality.
__global__ __launch_bounds__(256, 3) void k_mega(MP p) {
    __shared__ short Xl[32][132];
    __shared__ short Hl[16][136];
    __shared__ float Lc[2][9][64];
    cooperative_groups::grid_group gg = cooperative_groups::this_grid();
    const int b = blockIdx.x, NB = gridDim.x;
    const int f = detect_f32(p.w_in);

    for (int idx = b * 256 + threadIdx.x; idx < 327680 + 768; idx += NB * 256)
        dev_prep(p, idx, f);
    gg.sync();
    for (int t = b; t < 1312; t += NB) dev_inm(p, f, t & 7, (t >> 3) % 41, (t >> 3) / 41, Xl);
    gg.sync();
    for (int t = b; t < 672;  t += NB) dev_conv(p, t & 7, (t >> 3) % 21, (t >> 3) / 21);
    gg.sync();
    for (int t = b; t < 1008; t += NB) dev_qkv(p, t & 7, (t >> 3) % 21, (t >> 3) / 21);
    gg.sync();
    for (int t = b; t < 1344; t += NB) dev_attn(p, t & 7, (t >> 3) % 21, (t >> 3) / 21, Lc);
    gg.sync();
    for (int t = b; t < 648;  t += NB) dev_cell(p, f, t & 7, t >> 3, Hl);
}

// ================= fallback wrappers (used only if cooperative launch fails) =================
__global__ __launch_bounds__(256) void kw_prep(MP p) {
    int f = detect_f32(p.w_in);
    int idx = blockIdx.x * 256 + threadIdx.x;
    if (idx < 327680 + 768) dev_prep(p, idx, f);
}
__global__ __launch_bounds__(256) void kw_inm(MP p) {
    __shared__ short Xl[32][132];
    int f = detect_f32(p.w_in);
    dev_inm(p, f, blockIdx.x, blockIdx.y, blockIdx.z, Xl);
}
__global__ __launch_bounds__(256) void kw_conv(MP p) {
    dev_conv(p, blockIdx.x, blockIdx.y, blockIdx.z);
}
__global__ __launch_bounds__(256) void kw_qkv(MP p) {
    dev_qkv(p, blockIdx.x, blockIdx.y, blockIdx.z);
}
__global__ __launch_bounds__(256) void kw_attn(MP p) {
    __shared__ float Lc[2][9][64];
    dev_attn(p, blockIdx.x, blockIdx.y, blockIdx.z, Lc);
}
__global__ __launch_bounds__(256) void kw_cell(MP p) {
    __shared__ short Hl[16][136];
    int f = detect_f32(p.w_in);
    dev_cell(p, f, blockIdx.x, blockIdx.y, Hl);
}

extern "C" void kernel_launch(void* const* d_in, const int* in_sizes, int n_in,
                              void* d_out, int out_size, void* d_ws, size_t ws_size,
                              hipStream_t stream) {
    char* ws = (char*)d_ws;
    bf16*  Wst  = (bf16*)(ws + 256);          // 327680 bf16
    float* Bst  = (float*)(ws + 655616);      // 768 f32
    bf16*  XT   = (bf16*)(ws + 1048576);      // channel-last [n][1296][128]
    bf16*  Zb   = XT + TT;
    bf16*  Qb   = Zb + TT;                    // head-grouped [n][8][1296][16]
    bf16*  Kb   = Qb + TT;
    bf16*  Vb   = Kb + TT;                    // channel-first [n][128][1296]
    bf16*  Ab   = Vb + TT;                    // ~17 MB total

    MP mp;
    mp.x = d_in[0];   mp.w_in = d_in[1];  mp.b_in = d_in[2];
    mp.w_conv = d_in[3]; mp.b_conv = d_in[4];
    mp.wq = d_in[5];  mp.wk = d_in[6];   mp.wv = d_in[7];
    mp.w_i = d_in[8]; mp.b_i = d_in[9];
    mp.w_g = d_in[12]; mp.b_g = d_in[13];
    mp.w_o = d_in[14]; mp.b_o = d_in[15];
    mp.w_out = d_in[16]; mp.b_out = d_in[17];
    mp.Wst = Wst; mp.Bst = Bst;
    mp.XT = XT; mp.Zb = Zb; mp.Qb = Qb; mp.Kb = Kb; mp.Vb = Vb; mp.Ab = Ab;
    mp.out = d_out;

    void* kargs[] = { &mp };
    hipError_t err = hipLaunchCooperativeKernel((const void*)k_mega,
                                                dim3(768), dim3(256),
                                                kargs, 0, stream);
    if (err != hipSuccess) {
        // fallback: identical device code as 6 ordinary dispatches
        kw_prep<<<1284, 256, 0, stream>>>(mp);
        kw_inm<<<dim3(8, 41, 4), 256, 0, stream>>>(mp);
        kw_conv<<<dim3(8, 21, 4), 256, 0, stream>>>(mp);
        kw_qkv<<<dim3(8, 21, 6), 256, 0, stream>>>(mp);
        kw_attn<<<dim3(8, 21, 8), 256, 0, stream>>>(mp);
        kw_cell<<<dim3(8, 81), 256, 0, stream>>>(mp);
    }
}

// Round 8
// 199.633 us; speedup vs baseline: 3.2607x; 3.2607x over previous
//
#include <hip/hip_runtime.h>
#include <hip/hip_bf16.h>
#include <math.h>

typedef __hip_bfloat16 bf16;
typedef __attribute__((ext_vector_type(8))) short frag8;
typedef __attribute__((ext_vector_type(4))) float f32x4;
typedef __attribute__((ext_vector_type(16))) float f32x16;
typedef __attribute__((ext_vector_type(2))) unsigned int u32x2;
typedef __attribute__((ext_vector_type(4))) unsigned int u32x4;

#define HW  1296
#define CH  128
#define TT  1327104   // 8 * 1296 * 128

__device__ __forceinline__ float b2f(bf16 v) { return __bfloat162float(v); }
__device__ __forceinline__ float bits2f(unsigned short u) {
    return __uint_as_float(((unsigned)u) << 16);
}
__device__ __forceinline__ float frcp(float x) { return __builtin_amdgcn_rcpf(x); }
__device__ __forceinline__ float fsigm(float x) { return frcp(1.0f + __expf(-x)); }
__device__ __forceinline__ float ftanh(float x) {
    float xc = fminf(15.0f, fmaxf(-15.0f, x));
    float e = __expf(2.0f * xc);
    return (e - 1.0f) * frcp(e + 1.0f);
}
// round-half-up f32->bf16 pair pack: 2 adds + 1 v_perm
__device__ __forceinline__ int packrh(float a, float b) {
    unsigned ua = __float_as_uint(a) + 0x8000u;
    unsigned ub = __float_as_uint(b) + 0x8000u;
    return (int)__builtin_amdgcn_perm(ub, ua, 0x07060302);
}
__device__ __forceinline__ int2 pack4(float a, float b, float c, float d) {
    int2 r; r.x = packrh(a, b); r.y = packrh(c, d); return r;
}
// packed RNE f32 pair -> bf16x2 in one VALU op
__device__ __forceinline__ unsigned cvtpk(float a, float b) {
    unsigned r;
    asm("v_cvt_pk_bf16_f32 %0, %1, %2" : "=v"(r) : "v"(a), "v"(b));
    return r;
}

// inline wave-uniform dtype detection (256 probe elems of w_in)
__device__ __forceinline__ int detect_f32(const void* w) {
    const short4* p = (const short4*)w;
    short4 v = p[threadIdx.x & 63];
    int bad = 0;
    #pragma unroll
    for (int j = 0; j < 4; ++j) {
        float f = bits2f(((const unsigned short*)&v)[j]);
        if (!(fabsf(f) <= 100.0f)) bad = 1;   // catches NaN/Inf too
    }
    return __any(bad) ? 1 : 0;
}

// ---------------- weight prep ----------------
// Wst (bf16): w_in[128o][128i]@0 | wconvT[9tap][128o][128r]@16384 |
//   wqkv[384o][128i]@163840 | wg[3][128o][256k]@212992 | wout[128o][128i]@311296
// Bst f32[768]: in@0 conv@128 i@256 g@384 o@512 out@640
// wq rows pre-scaled by log2(e) so attention uses exp2 directly.
__global__ __launch_bounds__(256) void k_prep(
    const void* w_in, const void* w_conv, const void* wq, const void* wk, const void* wv,
    const void* w_i, const void* w_g, const void* w_o, const void* w_out,
    const void* b_in, const void* b_conv, const void* b_i, const void* b_g,
    const void* b_o, const void* b_out,
    bf16* __restrict__ Wdst, float* __restrict__ Bdst)
{
    int idx = blockIdx.x * 256 + threadIdx.x;
    const int f = detect_f32(w_in);
    if (idx < 327680) {
        const void* src; int si;
        if (idx < 16384)       { src = w_in; si = idx; }   // native [o][i]
        else if (idx < 163840) { int j = idx - 16384; int tap = j >> 14, rem = j & 16383;
                                 int o = rem >> 7, r = rem & 127;
                                 src = w_conv; si = o * 2304 + r * 9 + tap; }
        else if (idx < 212992) { int j = idx - 163840; int o = j >> 7, i = j & 127;
                                 int ws_ = o >> 7;
                                 src = ws_ == 0 ? wq : ws_ == 1 ? wk : wv;
                                 si = (o & 127) * 128 + i; }
        else if (idx < 311296) { int j = idx - 212992; int g = j >> 15, rem = j & 32767;
                                 int o = rem >> 8, k = rem & 255;
                                 src = g == 0 ? w_i : g == 1 ? w_g : w_o; si = o * 256 + k; }
        else                   { int j = idx - 311296; int o = j >> 7, i = j & 127;
                                 src = w_out; si = o * 128 + i; }
        float v = f ? ((const float*)src)[si] : b2f(((const bf16*)src)[si]);
        if (idx >= 163840 && idx < 180224) v *= 1.4426950408889634f;  // wq * log2(e)
        Wdst[idx] = __float2bfloat16(v);
    } else if (idx < 327680 + 768) {
        int j = idx - 327680; int b = j >> 7, e = j & 127;
        const void* src = b == 0 ? b_in : b == 1 ? b_conv : b == 2 ? b_i
                        : b == 3 ? b_g : b == 4 ? b_o : b_out;
        Bdst[j] = f ? ((const float*)src)[e] : b2f(((const bf16*)src)[e]);
    }
}

// ---------------- k_inm: fused transpose + MFMA GEMM + tanh ----------------
// grid (8 n, 41 ptile, 4 otile) — n on blockIdx.x => per-batch XCD locality.
__global__ __launch_bounds__(256) void k_inm(const void* __restrict__ x,
                                             const void* __restrict__ wraw,
                                             const bf16* __restrict__ Wm,   // [o][i]
                                             const float* __restrict__ bias,
                                             bf16* __restrict__ XT) {
    __shared__ short Xl[32][132];
    const int tid = threadIdx.x, wave = tid >> 6, lane = tid & 63;
    const int quad = lane >> 4, l16 = lane & 15;
    const int n = blockIdx.x;
    const int pbase = blockIdx.y * 32;
    const int obase = blockIdx.z * 32 + (wave & 1) * 16;
    const int pstrip = (wave >> 1) * 16;
    const int f = detect_f32(wraw);

    // weight frags are LDS-independent: issue up front (overlap staging+barrier)
    frag8 WF[4];
    #pragma unroll
    for (int kc = 0; kc < 4; ++kc)
        WF[kc] = *(const frag8*)&Wm[(obase + l16) * CH + kc * 32 + quad * 8];

    #pragma unroll
    for (int rep = 0; rep < 4; ++rep) {
        int u = tid + rep * 256;
        int i = u >> 3;
        int p4 = (u & 7) * 4;
        int p = pbase + p4;
        short4 s = {0, 0, 0, 0};
        if (p < HW) {
            size_t gi = (size_t)n * CH * HW + (size_t)i * HW + p;
            if (f) {
                float4 fv = *(const float4*)((const float*)x + gi);
                int2 pk = pack4(fv.x, fv.y, fv.z, fv.w);
                s = *(short4*)&pk;
            } else {
                s = *(const short4*)((const bf16*)x + gi);
            }
        }
        Xl[p4 + 0][i] = s.x; Xl[p4 + 1][i] = s.y;
        Xl[p4 + 2][i] = s.z; Xl[p4 + 3][i] = s.w;
    }
    __syncthreads();

    const int pl = pstrip + l16;
    f32x4 acc = {0.f, 0.f, 0.f, 0.f};
    #pragma unroll
    for (int kc = 0; kc < 4; ++kc) {
        int k = kc * 32 + quad * 8;
        short4 b0 = *(const short4*)&Xl[pl][k];
        short4 b1 = *(const short4*)&Xl[pl][k + 4];
        frag8 bf = {b0.x, b0.y, b0.z, b0.w, b1.x, b1.y, b1.z, b1.w};
        acc = __builtin_amdgcn_mfma_f32_16x16x32_bf16(WF[kc], bf, acc, 0, 0, 0);
    }

    int p = pbase + pstrip + l16;
    if (p < HW) {
        int og = obase + quad * 4;
        int2 pk = pack4(ftanh(acc[0] + bias[og + 0]), ftanh(acc[1] + bias[og + 1]),
                        ftanh(acc[2] + bias[og + 2]), ftanh(acc[3] + bias[og + 3]));
        *(int2*)((short*)XT + ((size_t)n * HW + p) * CH + og) = pk;
    }
}

// ---------------- k_cq: FUSED 3x3 conv + QKV projection ----------------
// grid (8 n, 41 ptile), 512 threads = 8 waves. Block owns 32p x ALL 128 conv
// outputs, so the (pointwise-in-p) qkv projection runs in-block from an LDS
// z-tile — deletes the k_qkv dispatch + its global Zb re-read. Zb still
// written once (k_cell consumes it).
// Conv phase: wave w = 16o x 32p (proven r4 shape), 2-deep tap pipeline.
// QKV phase: 12 otiles of 32o x 32p; wave w does otile w (Q/K) and w<4 also
// otile 8+w (V, swapped operands -> channel-first store).
__global__ __launch_bounds__(512) void k_cq(
    const bf16* __restrict__ XT, const bf16* __restrict__ Wc,
    const float* __restrict__ bc, const bf16* __restrict__ Wqkv,
    bf16* __restrict__ Zb, bf16* __restrict__ Qb, bf16* __restrict__ Kb,
    bf16* __restrict__ Vb)
{
    __shared__ short Zl[32][136];   // 272B rows: 16B-aligned
    const int tid = threadIdx.x, w = tid >> 6, lane = tid & 63;
    const int quad = lane >> 4, l16 = lane & 15;
    const int n = blockIdx.x;
    const int pbase = blockIdx.y * 32;
    const bf16* actn = XT + (size_t)n * HW * CH;

    // ---- conv phase: wave w owns o [w*16, w*16+16) x 32p ----
    const int obase = w * 16;
    const int p1 = pbase + l16, p2 = pbase + 16 + l16;
    const bool p1ok = p1 < HW, p2ok = p2 < HW;
    const int h1 = p1 / 36, w1 = p1 - h1 * 36;
    const int h2 = p2 / 36, w2 = p2 - h2 * 36;

    frag8 zf = {0, 0, 0, 0, 0, 0, 0, 0};
    f32x4 acc[2];
    acc[0] = (f32x4){0.f, 0.f, 0.f, 0.f};
    acc[1] = (f32x4){0.f, 0.f, 0.f, 0.f};

    frag8 A1[2][4], A2[2][4], WT[2][4];

    #define LOADTAP(TAP, BUF)                                                        \
    {                                                                                \
        const int dy = (TAP) / 3 - 1, dx = (TAP) - ((TAP) / 3) * 3 - 1;              \
        const bool ok1 = p1ok && (unsigned)(h1 + dy) < 36u && (unsigned)(w1 + dx) < 36u; \
        const bool ok2 = p2ok && (unsigned)(h2 + dy) < 36u && (unsigned)(w2 + dx) < 36u; \
        const int sh = dy * 36 + dx;                                                 \
        const bf16* a1 = actn + (size_t)(p1 + sh) * CH + quad * 8;                   \
        const bf16* a2 = actn + (size_t)(p2 + sh) * CH + quad * 8;                   \
        const bf16* wp = Wc + (TAP) * 16384 + (obase + l16) * CH + quad * 8;         \
        _Pragma("unroll")                                                            \
        for (int kc = 0; kc < 4; ++kc) {                                             \
            A1[BUF][kc] = ok1 ? *(const frag8*)&a1[kc * 32] : zf;                    \
            A2[BUF][kc] = ok2 ? *(const frag8*)&a2[kc * 32] : zf;                    \
            WT[BUF][kc] = *(const frag8*)&wp[kc * 32];                               \
        }                                                                            \
    }

    LOADTAP(0, 0);
    #pragma unroll
    for (int tap = 0; tap < 9; ++tap) {
        const int cur = tap & 1;
        if (tap < 8) LOADTAP(tap + 1, cur ^ 1);
        #pragma unroll
        for (int kc = 0; kc < 4; ++kc) {
            acc[0] = __builtin_amdgcn_mfma_f32_16x16x32_bf16(WT[cur][kc], A1[cur][kc], acc[0], 0, 0, 0);
            acc[1] = __builtin_amdgcn_mfma_f32_16x16x32_bf16(WT[cur][kc], A2[cur][kc], acc[1], 0, 0, 0);
        }
    }
    #undef LOADTAP

    // epilogue: z -> global Zb (guarded) + LDS Zl (always; OOB rows hold finite
    // garbage consumed only by discarded outputs)
    const int og = obase + quad * 4;
    #pragma unroll
    for (int pt = 0; pt < 2; ++pt) {
        int p = pbase + pt * 16 + l16;
        int2 pk = pack4(acc[pt][0] + bc[og + 0], acc[pt][1] + bc[og + 1],
                        acc[pt][2] + bc[og + 2], acc[pt][3] + bc[og + 3]);
        *(int2*)&Zl[pt * 16 + l16][og] = pk;
        if (p < HW)
            *(int2*)((short*)Zb + ((size_t)n * HW + p) * CH + og) = pk;
    }
    __syncthreads();

    // ---- qkv phase ----
    for (int ot = w; ot < 12; ot += 8) {
        const bool vt = (ot >= 8);          // wave-uniform
        const int ob = ot * 32;
        frag8 B1[4], B2[4], W0a[4], W1a[4];
        #pragma unroll
        for (int kc = 0; kc < 4; ++kc) {
            int ko = kc * 32 + quad * 8;
            B1[kc]  = *(const frag8*)&Zl[l16][ko];
            B2[kc]  = *(const frag8*)&Zl[16 + l16][ko];
            W0a[kc] = *(const frag8*)&Wqkv[(size_t)(ob + l16) * CH + ko];
            W1a[kc] = *(const frag8*)&Wqkv[(size_t)(ob + 16 + l16) * CH + ko];
        }

        f32x4 qacc[2][2];   // [of][pt]
        #pragma unroll
        for (int of = 0; of < 2; ++of) {
            qacc[of][0] = (f32x4){0.f, 0.f, 0.f, 0.f};
            qacc[of][1] = (f32x4){0.f, 0.f, 0.f, 0.f};
        }
        #pragma unroll
        for (int kc = 0; kc < 4; ++kc) {
            if (vt) {
                qacc[0][0] = __builtin_amdgcn_mfma_f32_16x16x32_bf16(B1[kc], W0a[kc], qacc[0][0], 0, 0, 0);
                qacc[0][1] = __builtin_amdgcn_mfma_f32_16x16x32_bf16(B2[kc], W0a[kc], qacc[0][1], 0, 0, 0);
                qacc[1][0] = __builtin_amdgcn_mfma_f32_16x16x32_bf16(B1[kc], W1a[kc], qacc[1][0], 0, 0, 0);
                qacc[1][1] = __builtin_amdgcn_mfma_f32_16x16x32_bf16(B2[kc], W1a[kc], qacc[1][1], 0, 0, 0);
            } else {
                qacc[0][0] = __builtin_amdgcn_mfma_f32_16x16x32_bf16(W0a[kc], B1[kc], qacc[0][0], 0, 0, 0);
                qacc[0][1] = __builtin_amdgcn_mfma_f32_16x16x32_bf16(W0a[kc], B2[kc], qacc[0][1], 0, 0, 0);
                qacc[1][0] = __builtin_amdgcn_mfma_f32_16x16x32_bf16(W1a[kc], B1[kc], qacc[1][0], 0, 0, 0);
                qacc[1][1] = __builtin_amdgcn_mfma_f32_16x16x32_bf16(W1a[kc], B2[kc], qacc[1][1], 0, 0, 0);
            }
        }

        if (vt) {
            #pragma unroll
            for (int of = 0; of < 2; ++of) {
                int ov = ob + of * 16 - 256 + l16;
                #pragma unroll
                for (int pt = 0; pt < 2; ++pt) {
                    int p4 = pbase + pt * 16 + quad * 4;
                    if (p4 >= HW) continue;
                    int2 pk = pack4(qacc[of][pt][0], qacc[of][pt][1], qacc[of][pt][2], qacc[of][pt][3]);
                    *(int2*)((short*)Vb + ((size_t)n * CH + ov) * HW + p4) = pk;
                }
            }
        } else {
            #pragma unroll
            for (int of = 0; of < 2; ++of) {
                int ogq = ob + of * 16 + quad * 4;
                int which = ogq >> 7, ol = ogq & 127;
                bf16* dst = which == 0 ? Qb : Kb;
                #pragma unroll
                for (int pt = 0; pt < 2; ++pt) {
                    int p = pbase + pt * 16 + l16;
                    if (p >= HW) continue;
                    size_t di = (((size_t)n * 8 + (ol >> 4)) * HW + p) * 16 + (ol & 15);
                    int2 pk = pack4(qacc[of][pt][0], qacc[of][pt][1], qacc[of][pt][2], qacc[of][pt][3]);
                    *(int2*)((short*)dst + di) = pk;
                }
            }
        }
    }
}

// ---------------- k_cell: gates GEMM + LSTM cell + fused out-projection ----------------
// grid (8 n, 81 ptile) — 81*16 = 1296 exactly, no p guards.
// Phase 1 (gates): 2-deep kc software pipeline (7 frags/stage in flight).
// Phase 2 (cell): h = o*tanh(i*g) -> LDS Hl[16][136].
// Phase 3 (out): W_out frags issued BEFORE the barrier; k_outm's verified
//   operand scheme -> channel-first store.
__global__ __launch_bounds__(256) void k_cell(
    const bf16* __restrict__ Zb, const bf16* __restrict__ Ab,
    const bf16* __restrict__ Wg, const float* __restrict__ bg,
    const bf16* __restrict__ Wo, const float* __restrict__ bo,
    void* __restrict__ out, const void* __restrict__ wraw)
{
    __shared__ short Hl[16][136];   // row stride 272B
    const int tid = threadIdx.x, w = tid >> 6, lane = tid & 63;
    const int quad = lane >> 4, l16 = lane & 15;
    const int n = blockIdx.x;
    const int pbase = blockIdx.y * 16;
    const int f32f = detect_f32(wraw);
    const bf16* zn = Zb + (size_t)n * HW * CH;
    const bf16* an = Ab + (size_t)n * HW * CH;

    const int obase = w * 32;
    const int p1 = pbase + l16;   // always < HW (81*16 == 1296)

    f32x4 acc[3][2];
    #pragma unroll
    for (int g = 0; g < 3; ++g) {
        acc[g][0] = (f32x4){0.f, 0.f, 0.f, 0.f};
        acc[g][1] = (f32x4){0.f, 0.f, 0.f, 0.f};
    }

    frag8 GB[2];
    frag8 GW[2][6];

    #define LOADG(KC, BUF)                                                           \
    {                                                                                \
        const bf16* src = ((KC) >= 4) ? an : zn;                                     \
        const int ko = ((KC) & 3) * 32 + quad * 8;                                   \
        GB[BUF] = *(const frag8*)&src[(size_t)p1 * CH + ko];                         \
        _Pragma("unroll")                                                            \
        for (int g = 0; g < 3; ++g) {                                                \
            _Pragma("unroll")                                                        \
            for (int of = 0; of < 2; ++of)                                           \
                GW[BUF][g * 2 + of] = *(const frag8*)&Wg[g * 32768 +                 \
                    (obase + of * 16 + l16) * 256 + (KC) * 32 + quad * 8];           \
        }                                                                            \
    }

    LOADG(0, 0);
    #pragma unroll
    for (int kc = 0; kc < 8; ++kc) {
        const int cur = kc & 1;
        if (kc < 7) LOADG(kc + 1, cur ^ 1);
        #pragma unroll
        for (int g = 0; g < 3; ++g) {
            #pragma unroll
            for (int of = 0; of < 2; ++of)
                acc[g][of] = __builtin_amdgcn_mfma_f32_16x16x32_bf16(
                    GW[cur][g * 2 + of], GB[cur], acc[g][of], 0, 0, 0);
        }
    }
    #undef LOADG

    // cell nonlinearity -> LDS h tile (C layout: row o = quad*4+r, col p = l16)
    #pragma unroll
    for (int of = 0; of < 2; ++of) {
        int og = obase + of * 16 + quad * 4;
        float hv[4];
        #pragma unroll
        for (int r = 0; r < 4; ++r) {
            int o = og + r;
            float iv = fsigm(acc[0][of][r] + bg[o]);
            float gv = ftanh(acc[1][of][r] + bg[128 + o]);
            float ov = fsigm(acc[2][of][r] + bg[256 + o]);
            hv[r] = ov * ftanh(iv * gv);
        }
        *(int2*)&Hl[l16][og] = pack4(hv[0], hv[1], hv[2], hv[3]);
    }

    // out-phase weight frags: LDS-independent, issue before the barrier
    frag8 OW[2][4];
    #pragma unroll
    for (int of = 0; of < 2; ++of)
        #pragma unroll
        for (int kc = 0; kc < 4; ++kc)
            OW[of][kc] = *(const frag8*)&Wo[(size_t)(obase + of * 16 + l16) * CH
                                            + kc * 32 + quad * 8];
    __syncthreads();

    f32x4 oc[2];
    oc[0] = (f32x4){0.f, 0.f, 0.f, 0.f};
    oc[1] = (f32x4){0.f, 0.f, 0.f, 0.f};
    #pragma unroll
    for (int kc = 0; kc < 4; ++kc) {
        int k = kc * 32 + quad * 8;
        short4 h0 = *(const short4*)&Hl[l16][k];
        short4 h1 = *(const short4*)&Hl[l16][k + 4];
        frag8 af = {h0.x, h0.y, h0.z, h0.w, h1.x, h1.y, h1.z, h1.w};
        #pragma unroll
        for (int of = 0; of < 2; ++of)
            oc[of] = __builtin_amdgcn_mfma_f32_16x16x32_bf16(af, OW[of][kc], oc[of], 0, 0, 0);
    }
    int p4 = pbase + quad * 4;
    #pragma unroll
    for (int of = 0; of < 2; ++of) {
        int o = obase + of * 16 + l16;
        float bv = bo[o];
        size_t di = ((size_t)n * CH + o) * HW + p4;
        if (f32f) {
            float4 fv = {oc[of][0] + bv, oc[of][1] + bv, oc[of][2] + bv, oc[of][3] + bv};
            *(float4*)&((float*)out)[di] = fv;
        } else {
            int2 pk = pack4(oc[of][0] + bv, oc[of][1] + bv, oc[of][2] + bv, oc[of][3] + bv);
            *(int2*)&((short*)out)[di] = pk;
        }
    }
}

// ---------------- MFMA flash attention v7: 32x32x16, d-split x2, S-pipelined ----------------
// grid (8 n, 11 qtile, 8 head), 512 threads = 8 waves: qw = w&3 (32 q each),
// dq = w>>2 (d-halves: chunks 0..19 / 20..40). Partial O/L over disjoint
// d-ranges combine additively (LDS, one barrier). Next chunk's QK^T issues
// before current exp2/pack; K prefetched 2 deep.
// S layout (m74/m101): col=q=lane&31, row=d_local=(r&3)+8*(r>>2)+4*(lane>>5).
// lsum free: V A-operand row c==16 all-ones -> Oacc[8] = sum_d P[d][q].
__global__ __launch_bounds__(512) void k_attn(const bf16* __restrict__ Qg,
                                              const bf16* __restrict__ Kg,
                                              const bf16* __restrict__ Vcf,
                                              bf16* __restrict__ A) {
    __shared__ float Lc[4][9][64];   // [qw][acc reg 0..7 + lsum][lane]

    const int tid = threadIdx.x;
    const int w = tid >> 6, lane = tid & 63;
    const int l32 = lane & 31, hi = lane >> 5;
    const int qw = w & 3, dq = w >> 2;
    const int n = blockIdx.x;
    const int head = blockIdx.z;
    const int qb = blockIdx.y * 128 + qw * 32;
    const int qtok = qb + l32;

    const short* Qh = (const short*)Qg + ((size_t)(n * 8 + head)) * HW * 16;
    const short* Kh = (const short*)Kg + ((size_t)(n * 8 + head)) * HW * 16;
    const short* Vh = (const short*)Vcf + ((size_t)n * CH + head * 16) * HW;

    frag8 qf = {0, 0, 0, 0, 0, 0, 0, 0};
    if (qtok < HW) qf = *(const frag8*)&Qh[(size_t)qtok * 16 + hi * 8];

    const short one = (short)0x3F80;
    const frag8 vones = {one, one, one, one, one, one, one, one};
    const frag8 vzero = {0, 0, 0, 0, 0, 0, 0, 0};
    const frag8 vfill = (l32 == 16) ? vones : vzero;
    const bool vload = l32 < 16;
    const short* Vrow = Vh + (size_t)(vload ? l32 : 0) * HW;

    const f32x16 zero16 = {};
    f32x16 Oacc = {};

    auto KLD = [&](int dd) -> frag8 {
        return *(const frag8*)&Kh[(size_t)(dd + l32) * 16 + hi * 8];
    };
    auto VLD = [&](int dd) -> frag8 {
        return vload ? *(const frag8*)&Vrow[dd + hi * 8] : vfill;
    };

    const int c0 = dq ? 20 : 0;
    frag8 kf  = KLD(c0 * 32);
    frag8 kf2 = KLD(c0 * 32 + 32);
    frag8 va  = VLD(c0 * 32);
    frag8 vb  = VLD(c0 * 32 + 16);
    f32x16 S = __builtin_amdgcn_mfma_f32_32x32x16_bf16(kf, qf, zero16, 0, 0, 0);

    for (int it = 0; it < 20; ++it) {
        const int d0 = (c0 + it) * 32;
        frag8 kn  = KLD(d0 + 64);
        frag8 van = VLD(d0 + 32);
        frag8 vbn = VLD(d0 + 48);
        f32x16 Sn = __builtin_amdgcn_mfma_f32_32x32x16_bf16(kf2, qf, zero16, 0, 0, 0);

        float p[16];
        #pragma unroll
        for (int r = 0; r < 16; ++r) p[r] = __builtin_amdgcn_exp2f(S[r]);

        #pragma unroll
        for (int hh = 0; hh < 2; ++hh) {
            unsigned P0 = cvtpk(p[hh * 8 + 0], p[hh * 8 + 1]);
            unsigned P1 = cvtpk(p[hh * 8 + 2], p[hh * 8 + 3]);
            unsigned P2 = cvtpk(p[hh * 8 + 4], p[hh * 8 + 5]);
            unsigned P3 = cvtpk(p[hh * 8 + 6], p[hh * 8 + 7]);
            u32x2 s02 = __builtin_amdgcn_permlane32_swap(P0, P2, false, false);
            u32x2 s13 = __builtin_amdgcn_permlane32_swap(P1, P3, false, false);
            u32x4 bw = {s02[0], s13[0], s02[1], s13[1]};
            frag8 pf = __builtin_bit_cast(frag8, bw);
            Oacc = __builtin_amdgcn_mfma_f32_32x32x16_bf16(hh ? vb : va, pf, Oacc, 0, 0, 0);
        }
        kf2 = kn; va = van; vb = vbn; S = Sn;
    }

    if (dq) {
        // tail chunk 40: d 1280..1295 = S rows 0..7 (already in S), V in va
        float p[8];
        #pragma unroll
        for (int r = 0; r < 8; ++r) p[r] = __builtin_amdgcn_exp2f(S[r]);
        unsigned P0 = cvtpk(p[0], p[1]);
        unsigned P1 = cvtpk(p[2], p[3]);
        unsigned P2 = cvtpk(p[4], p[5]);
        unsigned P3 = cvtpk(p[6], p[7]);
        u32x2 s02 = __builtin_amdgcn_permlane32_swap(P0, P2, false, false);
        u32x2 s13 = __builtin_amdgcn_permlane32_swap(P1, P3, false, false);
        u32x4 bw = {s02[0], s13[0], s02[1], s13[1]};
        frag8 pf = __builtin_bit_cast(frag8, bw);
        Oacc = __builtin_amdgcn_mfma_f32_32x32x16_bf16(va, pf, Oacc, 0, 0, 0);
        #pragma unroll
        for (int r = 0; r < 8; ++r) Lc[qw][r][lane] = Oacc[r];
        Lc[qw][8][lane] = Oacc[8];
    }
    __syncthreads();
    if (dq == 0) {
        #pragma unroll
        for (int r = 0; r < 8; ++r) Oacc[r] += Lc[qw][r][lane];
        float lsum = Oacc[8] + Lc[qw][8][lane];
        u32x2 lb = __builtin_amdgcn_permlane32_swap(__float_as_uint(lsum),
                                                    __float_as_uint(lsum), false, false);
        float inv = frcp(__uint_as_float(lb[0]));
        if (qtok < HW) {
            short* An = (short*)A + ((size_t)n * HW + qtok) * CH + head * 16;
            int2 pk0 = pack4(Oacc[0] * inv, Oacc[1] * inv, Oacc[2] * inv, Oacc[3] * inv);
            int2 pk1 = pack4(Oacc[4] * inv, Oacc[5] * inv, Oacc[6] * inv, Oacc[7] * inv);
            *(int2*)&An[hi * 4] = pk0;
            *(int2*)&An[8 + hi * 4] = pk1;
        }
    }
}

extern "C" void kernel_launch(void* const* d_in, const int* in_sizes, int n_in,
                              void* d_out, int out_size, void* d_ws, size_t ws_size,
                              hipStream_t stream) {
    char* ws = (char*)d_ws;
    bf16*  Wst  = (bf16*)(ws + 256);          // 327680 bf16
    float* Bst  = (float*)(ws + 655616);      // 768 f32
    bf16*  XT   = (bf16*)(ws + 1048576);      // channel-last [n][1296][128]
    bf16*  Zb   = XT + TT;
    bf16*  Qb   = Zb + TT;                    // head-grouped [n][8][1296][16]
    bf16*  Kb   = Qb + TT;
    bf16*  Vb   = Kb + TT;                    // channel-first [n][128][1296]
    bf16*  Ab   = Vb + TT;                    // ~17 MB total

    k_prep<<<1284, 256, 0, stream>>>(d_in[1], d_in[3], d_in[5], d_in[6], d_in[7],
                                     d_in[8], d_in[12], d_in[14], d_in[16],
                                     d_in[2], d_in[4], d_in[9], d_in[13], d_in[15], d_in[17],
                                     Wst, Bst);
    // n on blockIdx.x (gridDim.x == 8): linear wg id % 8 == n -> per-batch XCD locality
    k_inm<<<dim3(8, 41, 4), 256, 0, stream>>>(d_in[0], d_in[1], Wst, Bst, XT);
    k_cq<<<dim3(8, 41), 512, 0, stream>>>(XT, Wst + 16384, Bst + 128, Wst + 163840,
                                          Zb, Qb, Kb, Vb);
    k_attn<<<dim3(8, 11, 8), 512, 0, stream>>>(Qb, Kb, Vb, Ab);
    k_cell<<<dim3(8, 81), 256, 0, stream>>>(Zb, Ab, Wst + 212992, Bst + 256,
                                            Wst + 311296, Bst + 640, d_out, d_in[1]);
}

// Round 9
// 185.002 us; speedup vs baseline: 3.5185x; 1.0791x over previous
//
#include <hip/hip_runtime.h>
#include <hip/hip_bf16.h>
#include <math.h>

typedef __hip_bfloat16 bf16;
typedef __attribute__((ext_vector_type(8))) short frag8;
typedef __attribute__((ext_vector_type(4))) float f32x4;
typedef __attribute__((ext_vector_type(16))) float f32x16;
typedef __attribute__((ext_vector_type(2))) unsigned int u32x2;
typedef __attribute__((ext_vector_type(4))) unsigned int u32x4;

#define HW  1296
#define CH  128
#define TT  1327104   // 8 * 1296 * 128

__device__ __forceinline__ float b2f(bf16 v) { return __bfloat162float(v); }
__device__ __forceinline__ float bits2f(unsigned short u) {
    return __uint_as_float(((unsigned)u) << 16);
}
__device__ __forceinline__ float frcp(float x) { return __builtin_amdgcn_rcpf(x); }
__device__ __forceinline__ float fsigm(float x) { return frcp(1.0f + __expf(-x)); }
__device__ __forceinline__ float ftanh(float x) {
    float xc = fminf(15.0f, fmaxf(-15.0f, x));
    float e = __expf(2.0f * xc);
    return (e - 1.0f) * frcp(e + 1.0f);
}
// round-half-up f32->bf16 pair pack: 2 adds + 1 v_perm
__device__ __forceinline__ int packrh(float a, float b) {
    unsigned ua = __float_as_uint(a) + 0x8000u;
    unsigned ub = __float_as_uint(b) + 0x8000u;
    return (int)__builtin_amdgcn_perm(ub, ua, 0x07060302);
}
__device__ __forceinline__ int2 pack4(float a, float b, float c, float d) {
    int2 r; r.x = packrh(a, b); r.y = packrh(c, d); return r;
}
// packed RNE f32 pair -> bf16x2 in one VALU op
__device__ __forceinline__ unsigned cvtpk(float a, float b) {
    unsigned r;
    asm("v_cvt_pk_bf16_f32 %0, %1, %2" : "=v"(r) : "v"(a), "v"(b));
    return r;
}

// inline wave-uniform dtype detection (256 probe elems of w_in)
__device__ __forceinline__ int detect_f32(const void* w) {
    const short4* p = (const short4*)w;
    short4 v = p[threadIdx.x & 63];
    int bad = 0;
    #pragma unroll
    for (int j = 0; j < 4; ++j) {
        float f = bits2f(((const unsigned short*)&v)[j]);
        if (!(fabsf(f) <= 100.0f)) bad = 1;   // catches NaN/Inf too
    }
    return __any(bad) ? 1 : 0;
}

// ---------------- weight prep ----------------
// Wst (bf16): w_in[128o][128i]@0 | wconvT[9tap][128o][128r]@16384 |
//   wqkv[384o][128i]@163840 | wg[3][128o][256k]@212992 | wout[128o][128i]@311296
// Bst f32[768]: in@0 conv@128 i@256 g@384 o@512 out@640
// wq rows pre-scaled by log2(e) so attention uses exp2 directly.
__global__ __launch_bounds__(256) void k_prep(
    const void* w_in, const void* w_conv, const void* wq, const void* wk, const void* wv,
    const void* w_i, const void* w_g, const void* w_o, const void* w_out,
    const void* b_in, const void* b_conv, const void* b_i, const void* b_g,
    const void* b_o, const void* b_out,
    bf16* __restrict__ Wdst, float* __restrict__ Bdst)
{
    int idx = blockIdx.x * 256 + threadIdx.x;
    const int f = detect_f32(w_in);
    if (idx < 327680) {
        const void* src; int si;
        if (idx < 16384)       { src = w_in; si = idx; }   // native [o][i]
        else if (idx < 163840) { int j = idx - 16384; int tap = j >> 14, rem = j & 16383;
                                 int o = rem >> 7, r = rem & 127;
                                 src = w_conv; si = o * 2304 + r * 9 + tap; }
        else if (idx < 212992) { int j = idx - 163840; int o = j >> 7, i = j & 127;
                                 int ws_ = o >> 7;
                                 src = ws_ == 0 ? wq : ws_ == 1 ? wk : wv;
                                 si = (o & 127) * 128 + i; }
        else if (idx < 311296) { int j = idx - 212992; int g = j >> 15, rem = j & 32767;
                                 int o = rem >> 8, k = rem & 255;
                                 src = g == 0 ? w_i : g == 1 ? w_g : w_o; si = o * 256 + k; }
        else                   { int j = idx - 311296; int o = j >> 7, i = j & 127;
                                 src = w_out; si = o * 128 + i; }
        float v = f ? ((const float*)src)[si] : b2f(((const bf16*)src)[si]);
        if (idx >= 163840 && idx < 180224) v *= 1.4426950408889634f;  // wq * log2(e)
        Wdst[idx] = __float2bfloat16(v);
    } else if (idx < 327680 + 768) {
        int j = idx - 327680; int b = j >> 7, e = j & 127;
        const void* src = b == 0 ? b_in : b == 1 ? b_conv : b == 2 ? b_i
                        : b == 3 ? b_g : b == 4 ? b_o : b_out;
        Bdst[j] = f ? ((const float*)src)[e] : b2f(((const bf16*)src)[e]);
    }
}

// ---------------- k_inm: fused transpose + MFMA GEMM + tanh ----------------
// grid (8 n, 41 ptile, 4 otile) — n on blockIdx.x => per-batch XCD locality.
__global__ __launch_bounds__(256) void k_inm(const void* __restrict__ x,
                                             const void* __restrict__ wraw,
                                             const bf16* __restrict__ Wm,   // [o][i]
                                             const float* __restrict__ bias,
                                             bf16* __restrict__ XT) {
    __shared__ short Xl[32][132];
    const int tid = threadIdx.x, wave = tid >> 6, lane = tid & 63;
    const int quad = lane >> 4, l16 = lane & 15;
    const int n = blockIdx.x;
    const int pbase = blockIdx.y * 32;
    const int obase = blockIdx.z * 32 + (wave & 1) * 16;
    const int pstrip = (wave >> 1) * 16;
    const int f = detect_f32(wraw);

    // weight frags are LDS-independent: issue up front (overlap staging+barrier)
    frag8 WF[4];
    #pragma unroll
    for (int kc = 0; kc < 4; ++kc)
        WF[kc] = *(const frag8*)&Wm[(obase + l16) * CH + kc * 32 + quad * 8];

    #pragma unroll
    for (int rep = 0; rep < 4; ++rep) {
        int u = tid + rep * 256;
        int i = u >> 3;
        int p4 = (u & 7) * 4;
        int p = pbase + p4;
        short4 s = {0, 0, 0, 0};
        if (p < HW) {
            size_t gi = (size_t)n * CH * HW + (size_t)i * HW + p;
            if (f) {
                float4 fv = *(const float4*)((const float*)x + gi);
                int2 pk = pack4(fv.x, fv.y, fv.z, fv.w);
                s = *(short4*)&pk;
            } else {
                s = *(const short4*)((const bf16*)x + gi);
            }
        }
        Xl[p4 + 0][i] = s.x; Xl[p4 + 1][i] = s.y;
        Xl[p4 + 2][i] = s.z; Xl[p4 + 3][i] = s.w;
    }
    __syncthreads();

    const int pl = pstrip + l16;
    f32x4 acc = {0.f, 0.f, 0.f, 0.f};
    #pragma unroll
    for (int kc = 0; kc < 4; ++kc) {
        int k = kc * 32 + quad * 8;
        short4 b0 = *(const short4*)&Xl[pl][k];
        short4 b1 = *(const short4*)&Xl[pl][k + 4];
        frag8 bf = {b0.x, b0.y, b0.z, b0.w, b1.x, b1.y, b1.z, b1.w};
        acc = __builtin_amdgcn_mfma_f32_16x16x32_bf16(WF[kc], bf, acc, 0, 0, 0);
    }

    int p = pbase + pstrip + l16;
    if (p < HW) {
        int og = obase + quad * 4;
        int2 pk = pack4(ftanh(acc[0] + bias[og + 0]), ftanh(acc[1] + bias[og + 1]),
                        ftanh(acc[2] + bias[og + 2]), ftanh(acc[3] + bias[og + 3]));
        *(int2*)((short*)XT + ((size_t)n * HW + p) * CH + og) = pk;
    }
}

// ---------------- k_cq: FUSED 3x3 conv (TAP-SPLIT x2) + QKV projection ----------------
// grid (8 n, 41 ptile), 512 threads = 8 waves.
// Conv phase: wave (o4 = w&3 -> 32o, tg = w>>2 -> taps 0..4 / 5..8). Each wave
// has 4 independent acc chains over 4-5 taps; tap-split DOUBLES the number of
// concurrently-loading waves at constant chains/wave (the axis r5/r6 never
// tested: r5 was 2x waves x 1 chain, r6 was constant waves). Partial accs
// combine via LDS reduce. QKV phase unchanged (verified r8 scheme).
__global__ __launch_bounds__(512) void k_cq(
    const bf16* __restrict__ XT, const bf16* __restrict__ Wc,
    const float* __restrict__ bc, const bf16* __restrict__ Wqkv,
    bf16* __restrict__ Zb, bf16* __restrict__ Qb, bf16* __restrict__ Kb,
    bf16* __restrict__ Vb)
{
    __shared__ short Zl[32][136];        // 8.7 KB, 272B rows
    __shared__ float Rd[4][4][4][64];    // 16 KB: [o4][of*2+pt][reg][lane]
    const int tid = threadIdx.x, w = tid >> 6, lane = tid & 63;
    const int quad = lane >> 4, l16 = lane & 15;
    const int n = blockIdx.x;
    const int pbase = blockIdx.y * 32;
    const bf16* actn = XT + (size_t)n * HW * CH;

    // ---- conv phase: wave (o4, tg); 32o x 32p x {taps 0-4 | 5-8} ----
    const int o4 = w & 3, tg = w >> 2;
    const int obase = o4 * 32;
    const int p1 = pbase + l16, p2 = pbase + 16 + l16;
    const bool p1ok = p1 < HW, p2ok = p2 < HW;
    const int h1 = p1 / 36, w1 = p1 - h1 * 36;
    const int h2 = p2 / 36, w2 = p2 - h2 * 36;

    frag8 zf = {0, 0, 0, 0, 0, 0, 0, 0};
    f32x4 acc[2][2];   // [of][pt]
    #pragma unroll
    for (int of = 0; of < 2; ++of) {
        acc[of][0] = (f32x4){0.f, 0.f, 0.f, 0.f};
        acc[of][1] = (f32x4){0.f, 0.f, 0.f, 0.f};
    }

    const int tap0 = tg ? 5 : 0, tap1 = tg ? 9 : 5;
    for (int tap = tap0; tap < tap1; ++tap) {
        const int dy = tap / 3 - 1, dx = tap - (tap / 3) * 3 - 1;
        const bool ok1 = p1ok && (unsigned)(h1 + dy) < 36u && (unsigned)(w1 + dx) < 36u;
        const bool ok2 = p2ok && (unsigned)(h2 + dy) < 36u && (unsigned)(w2 + dx) < 36u;
        const int sh = dy * 36 + dx;
        const bf16* a1 = actn + (size_t)(p1 + sh) * CH + quad * 8;
        const bf16* a2 = actn + (size_t)(p2 + sh) * CH + quad * 8;
        const bf16* wp0 = Wc + tap * 16384 + (obase + l16) * CH + quad * 8;
        const bf16* wp1 = Wc + tap * 16384 + (obase + 16 + l16) * CH + quad * 8;
        frag8 A1[4], A2[4], W0[4], W1[4];
        #pragma unroll
        for (int kc = 0; kc < 4; ++kc) {
            A1[kc] = ok1 ? *(const frag8*)&a1[kc * 32] : zf;
            A2[kc] = ok2 ? *(const frag8*)&a2[kc * 32] : zf;
            W0[kc] = *(const frag8*)&wp0[kc * 32];
            W1[kc] = *(const frag8*)&wp1[kc * 32];
        }
        #pragma unroll
        for (int kc = 0; kc < 4; ++kc) {
            acc[0][0] = __builtin_amdgcn_mfma_f32_16x16x32_bf16(W0[kc], A1[kc], acc[0][0], 0, 0, 0);
            acc[0][1] = __builtin_amdgcn_mfma_f32_16x16x32_bf16(W0[kc], A2[kc], acc[0][1], 0, 0, 0);
            acc[1][0] = __builtin_amdgcn_mfma_f32_16x16x32_bf16(W1[kc], A1[kc], acc[1][0], 0, 0, 0);
            acc[1][1] = __builtin_amdgcn_mfma_f32_16x16x32_bf16(W1[kc], A2[kc], acc[1][1], 0, 0, 0);
        }
    }

    // tg=1 publishes partials; tg=0 reduces + epilogue
    if (tg == 1) {
        #pragma unroll
        for (int of = 0; of < 2; ++of)
            #pragma unroll
            for (int pt = 0; pt < 2; ++pt)
                #pragma unroll
                for (int r = 0; r < 4; ++r)
                    Rd[o4][of * 2 + pt][r][lane] = acc[of][pt][r];
    }
    __syncthreads();
    if (tg == 0) {
        #pragma unroll
        for (int of = 0; of < 2; ++of) {
            #pragma unroll
            for (int pt = 0; pt < 2; ++pt) {
                #pragma unroll
                for (int r = 0; r < 4; ++r)
                    acc[of][pt][r] += Rd[o4][of * 2 + pt][r][lane];
                int og = obase + of * 16 + quad * 4;
                int pl = pt * 16 + l16;
                int p = pbase + pl;
                int2 pk = pack4(acc[of][pt][0] + bc[og + 0], acc[of][pt][1] + bc[og + 1],
                                acc[of][pt][2] + bc[og + 2], acc[of][pt][3] + bc[og + 3]);
                *(int2*)&Zl[pl][og] = pk;
                if (p < HW)
                    *(int2*)((short*)Zb + ((size_t)n * HW + p) * CH + og) = pk;
            }
        }
    }
    __syncthreads();

    // ---- qkv phase (unchanged from r8) ----
    for (int ot = w; ot < 12; ot += 8) {
        const bool vt = (ot >= 8);          // wave-uniform
        const int ob = ot * 32;
        frag8 B1[4], B2[4], W0a[4], W1a[4];
        #pragma unroll
        for (int kc = 0; kc < 4; ++kc) {
            int ko = kc * 32 + quad * 8;
            B1[kc]  = *(const frag8*)&Zl[l16][ko];
            B2[kc]  = *(const frag8*)&Zl[16 + l16][ko];
            W0a[kc] = *(const frag8*)&Wqkv[(size_t)(ob + l16) * CH + ko];
            W1a[kc] = *(const frag8*)&Wqkv[(size_t)(ob + 16 + l16) * CH + ko];
        }

        f32x4 qacc[2][2];   // [of][pt]
        #pragma unroll
        for (int of = 0; of < 2; ++of) {
            qacc[of][0] = (f32x4){0.f, 0.f, 0.f, 0.f};
            qacc[of][1] = (f32x4){0.f, 0.f, 0.f, 0.f};
        }
        #pragma unroll
        for (int kc = 0; kc < 4; ++kc) {
            if (vt) {
                qacc[0][0] = __builtin_amdgcn_mfma_f32_16x16x32_bf16(B1[kc], W0a[kc], qacc[0][0], 0, 0, 0);
                qacc[0][1] = __builtin_amdgcn_mfma_f32_16x16x32_bf16(B2[kc], W0a[kc], qacc[0][1], 0, 0, 0);
                qacc[1][0] = __builtin_amdgcn_mfma_f32_16x16x32_bf16(B1[kc], W1a[kc], qacc[1][0], 0, 0, 0);
                qacc[1][1] = __builtin_amdgcn_mfma_f32_16x16x32_bf16(B2[kc], W1a[kc], qacc[1][1], 0, 0, 0);
            } else {
                qacc[0][0] = __builtin_amdgcn_mfma_f32_16x16x32_bf16(W0a[kc], B1[kc], qacc[0][0], 0, 0, 0);
                qacc[0][1] = __builtin_amdgcn_mfma_f32_16x16x32_bf16(W0a[kc], B2[kc], qacc[0][1], 0, 0, 0);
                qacc[1][0] = __builtin_amdgcn_mfma_f32_16x16x32_bf16(W1a[kc], B1[kc], qacc[1][0], 0, 0, 0);
                qacc[1][1] = __builtin_amdgcn_mfma_f32_16x16x32_bf16(W1a[kc], B2[kc], qacc[1][1], 0, 0, 0);
            }
        }

        if (vt) {
            #pragma unroll
            for (int of = 0; of < 2; ++of) {
                int ov = ob + of * 16 - 256 + l16;
                #pragma unroll
                for (int pt = 0; pt < 2; ++pt) {
                    int p4 = pbase + pt * 16 + quad * 4;
                    if (p4 >= HW) continue;
                    int2 pk = pack4(qacc[of][pt][0], qacc[of][pt][1], qacc[of][pt][2], qacc[of][pt][3]);
                    *(int2*)((short*)Vb + ((size_t)n * CH + ov) * HW + p4) = pk;
                }
            }
        } else {
            #pragma unroll
            for (int of = 0; of < 2; ++of) {
                int ogq = ob + of * 16 + quad * 4;
                int which = ogq >> 7, ol = ogq & 127;
                bf16* dst = which == 0 ? Qb : Kb;
                #pragma unroll
                for (int pt = 0; pt < 2; ++pt) {
                    int p = pbase + pt * 16 + l16;
                    if (p >= HW) continue;
                    size_t di = (((size_t)n * 8 + (ol >> 4)) * HW + p) * 16 + (ol & 15);
                    int2 pk = pack4(qacc[of][pt][0], qacc[of][pt][1], qacc[of][pt][2], qacc[of][pt][3]);
                    *(int2*)((short*)dst + di) = pk;
                }
            }
        }
    }
}

// ---------------- k_cell: gates GEMM + LSTM cell + fused out-projection ----------------
// grid (8 n, 81 ptile) — 81*16 = 1296 exactly, no p guards.
__global__ __launch_bounds__(256) void k_cell(
    const bf16* __restrict__ Zb, const bf16* __restrict__ Ab,
    const bf16* __restrict__ Wg, const float* __restrict__ bg,
    const bf16* __restrict__ Wo, const float* __restrict__ bo,
    void* __restrict__ out, const void* __restrict__ wraw)
{
    __shared__ short Hl[16][136];   // row stride 272B
    const int tid = threadIdx.x, w = tid >> 6, lane = tid & 63;
    const int quad = lane >> 4, l16 = lane & 15;
    const int n = blockIdx.x;
    const int pbase = blockIdx.y * 16;
    const int f32f = detect_f32(wraw);
    const bf16* zn = Zb + (size_t)n * HW * CH;
    const bf16* an = Ab + (size_t)n * HW * CH;

    const int obase = w * 32;
    const int p1 = pbase + l16;   // always < HW (81*16 == 1296)

    f32x4 acc[3][2];
    #pragma unroll
    for (int g = 0; g < 3; ++g) {
        acc[g][0] = (f32x4){0.f, 0.f, 0.f, 0.f};
        acc[g][1] = (f32x4){0.f, 0.f, 0.f, 0.f};
    }

    frag8 GB[2];
    frag8 GW[2][6];

    #define LOADG(KC, BUF)                                                           \
    {                                                                                \
        const bf16* src = ((KC) >= 4) ? an : zn;                                     \
        const int ko = ((KC) & 3) * 32 + quad * 8;                                   \
        GB[BUF] = *(const frag8*)&src[(size_t)p1 * CH + ko];                         \
        _Pragma("unroll")                                                            \
        for (int g = 0; g < 3; ++g) {                                                \
            _Pragma("unroll")                                                        \
            for (int of = 0; of < 2; ++of)                                           \
                GW[BUF][g * 2 + of] = *(const frag8*)&Wg[g * 32768 +                 \
                    (obase + of * 16 + l16) * 256 + (KC) * 32 + quad * 8];           \
        }                                                                            \
    }

    LOADG(0, 0);
    #pragma unroll
    for (int kc = 0; kc < 8; ++kc) {
        const int cur = kc & 1;
        if (kc < 7) LOADG(kc + 1, cur ^ 1);
        #pragma unroll
        for (int g = 0; g < 3; ++g) {
            #pragma unroll
            for (int of = 0; of < 2; ++of)
                acc[g][of] = __builtin_amdgcn_mfma_f32_16x16x32_bf16(
                    GW[cur][g * 2 + of], GB[cur], acc[g][of], 0, 0, 0);
        }
    }
    #undef LOADG

    // cell nonlinearity -> LDS h tile (C layout: row o = quad*4+r, col p = l16)
    #pragma unroll
    for (int of = 0; of < 2; ++of) {
        int og = obase + of * 16 + quad * 4;
        float hv[4];
        #pragma unroll
        for (int r = 0; r < 4; ++r) {
            int o = og + r;
            float iv = fsigm(acc[0][of][r] + bg[o]);
            float gv = ftanh(acc[1][of][r] + bg[128 + o]);
            float ov = fsigm(acc[2][of][r] + bg[256 + o]);
            hv[r] = ov * ftanh(iv * gv);
        }
        *(int2*)&Hl[l16][og] = pack4(hv[0], hv[1], hv[2], hv[3]);
    }

    // out-phase weight frags: LDS-independent, issue before the barrier
    frag8 OW[2][4];
    #pragma unroll
    for (int of = 0; of < 2; ++of)
        #pragma unroll
        for (int kc = 0; kc < 4; ++kc)
            OW[of][kc] = *(const frag8*)&Wo[(size_t)(obase + of * 16 + l16) * CH
                                            + kc * 32 + quad * 8];
    __syncthreads();

    f32x4 oc[2];
    oc[0] = (f32x4){0.f, 0.f, 0.f, 0.f};
    oc[1] = (f32x4){0.f, 0.f, 0.f, 0.f};
    #pragma unroll
    for (int kc = 0; kc < 4; ++kc) {
        int k = kc * 32 + quad * 8;
        short4 h0 = *(const short4*)&Hl[l16][k];
        short4 h1 = *(const short4*)&Hl[l16][k + 4];
        frag8 af = {h0.x, h0.y, h0.z, h0.w, h1.x, h1.y, h1.z, h1.w};
        #pragma unroll
        for (int of = 0; of < 2; ++of)
            oc[of] = __builtin_amdgcn_mfma_f32_16x16x32_bf16(af, OW[of][kc], oc[of], 0, 0, 0);
    }
    int p4 = pbase + quad * 4;
    #pragma unroll
    for (int of = 0; of < 2; ++of) {
        int o = obase + of * 16 + l16;
        float bv = bo[o];
        size_t di = ((size_t)n * CH + o) * HW + p4;
        if (f32f) {
            float4 fv = {oc[of][0] + bv, oc[of][1] + bv, oc[of][2] + bv, oc[of][3] + bv};
            *(float4*)&((float*)out)[di] = fv;
        } else {
            int2 pk = pack4(oc[of][0] + bv, oc[of][1] + bv, oc[of][2] + bv, oc[of][3] + bv);
            *(int2*)&((short*)out)[di] = pk;
        }
    }
}

// ---------------- MFMA flash attention v7: 32x32x16, d-split x2, S-pipelined ----------------
// grid (8 n, 11 qtile, 8 head), 512 threads = 8 waves: qw = w&3 (32 q each),
// dq = w>>2 (d-halves: chunks 0..19 / 20..40). Partial O/L over disjoint
// d-ranges combine additively (LDS, one barrier).
// S layout (m74/m101): col=q=lane&31, row=d_local=(r&3)+8*(r>>2)+4*(lane>>5).
// lsum free: V A-operand row c==16 all-ones -> Oacc[8] = sum_d P[d][q].
__global__ __launch_bounds__(512) void k_attn(const bf16* __restrict__ Qg,
                                              const bf16* __restrict__ Kg,
                                              const bf16* __restrict__ Vcf,
                                              bf16* __restrict__ A) {
    __shared__ float Lc[4][9][64];   // [qw][acc reg 0..7 + lsum][lane]

    const int tid = threadIdx.x;
    const int w = tid >> 6, lane = tid & 63;
    const int l32 = lane & 31, hi = lane >> 5;
    const int qw = w & 3, dq = w >> 2;
    const int n = blockIdx.x;
    const int head = blockIdx.z;
    const int qb = blockIdx.y * 128 + qw * 32;
    const int qtok = qb + l32;

    const short* Qh = (const short*)Qg + ((size_t)(n * 8 + head)) * HW * 16;
    const short* Kh = (const short*)Kg + ((size_t)(n * 8 + head)) * HW * 16;
    const short* Vh = (const short*)Vcf + ((size_t)n * CH + head * 16) * HW;

    frag8 qf = {0, 0, 0, 0, 0, 0, 0, 0};
    if (qtok < HW) qf = *(const frag8*)&Qh[(size_t)qtok * 16 + hi * 8];

    const short one = (short)0x3F80;
    const frag8 vones = {one, one, one, one, one, one, one, one};
    const frag8 vzero = {0, 0, 0, 0, 0, 0, 0, 0};
    const frag8 vfill = (l32 == 16) ? vones : vzero;
    const bool vload = l32 < 16;
    const short* Vrow = Vh + (size_t)(vload ? l32 : 0) * HW;

    const f32x16 zero16 = {};
    f32x16 Oacc = {};

    auto KLD = [&](int dd) -> frag8 {
        return *(const frag8*)&Kh[(size_t)(dd + l32) * 16 + hi * 8];
    };
    auto VLD = [&](int dd) -> frag8 {
        return vload ? *(const frag8*)&Vrow[dd + hi * 8] : vfill;
    };

    const int c0 = dq ? 20 : 0;
    frag8 kf  = KLD(c0 * 32);
    frag8 kf2 = KLD(c0 * 32 + 32);
    frag8 va  = VLD(c0 * 32);
    frag8 vb  = VLD(c0 * 32 + 16);
    f32x16 S = __builtin_amdgcn_mfma_f32_32x32x16_bf16(kf, qf, zero16, 0, 0, 0);

    for (int it = 0; it < 20; ++it) {
        const int d0 = (c0 + it) * 32;
        frag8 kn  = KLD(d0 + 64);
        frag8 van = VLD(d0 + 32);
        frag8 vbn = VLD(d0 + 48);
        f32x16 Sn = __builtin_amdgcn_mfma_f32_32x32x16_bf16(kf2, qf, zero16, 0, 0, 0);

        float p[16];
        #pragma unroll
        for (int r = 0; r < 16; ++r) p[r] = __builtin_amdgcn_exp2f(S[r]);

        #pragma unroll
        for (int hh = 0; hh < 2; ++hh) {
            unsigned P0 = cvtpk(p[hh * 8 + 0], p[hh * 8 + 1]);
            unsigned P1 = cvtpk(p[hh * 8 + 2], p[hh * 8 + 3]);
            unsigned P2 = cvtpk(p[hh * 8 + 4], p[hh * 8 + 5]);
            unsigned P3 = cvtpk(p[hh * 8 + 6], p[hh * 8 + 7]);
            u32x2 s02 = __builtin_amdgcn_permlane32_swap(P0, P2, false, false);
            u32x2 s13 = __builtin_amdgcn_permlane32_swap(P1, P3, false, false);
            u32x4 bw = {s02[0], s13[0], s02[1], s13[1]};
            frag8 pf = __builtin_bit_cast(frag8, bw);
            Oacc = __builtin_amdgcn_mfma_f32_32x32x16_bf16(hh ? vb : va, pf, Oacc, 0, 0, 0);
        }
        kf2 = kn; va = van; vb = vbn; S = Sn;
    }

    if (dq) {
        // tail chunk 40: d 1280..1295 = S rows 0..7 (already in S), V in va
        float p[8];
        #pragma unroll
        for (int r = 0; r < 8; ++r) p[r] = __builtin_amdgcn_exp2f(S[r]);
        unsigned P0 = cvtpk(p[0], p[1]);
        unsigned P1 = cvtpk(p[2], p[3]);
        unsigned P2 = cvtpk(p[4], p[5]);
        unsigned P3 = cvtpk(p[6], p[7]);
        u32x2 s02 = __builtin_amdgcn_permlane32_swap(P0, P2, false, false);
        u32x2 s13 = __builtin_amdgcn_permlane32_swap(P1, P3, false, false);
        u32x4 bw = {s02[0], s13[0], s02[1], s13[1]};
        frag8 pf = __builtin_bit_cast(frag8, bw);
        Oacc = __builtin_amdgcn_mfma_f32_32x32x16_bf16(va, pf, Oacc, 0, 0, 0);
        #pragma unroll
        for (int r = 0; r < 8; ++r) Lc[qw][r][lane] = Oacc[r];
        Lc[qw][8][lane] = Oacc[8];
    }
    __syncthreads();
    if (dq == 0) {
        #pragma unroll
        for (int r = 0; r < 8; ++r) Oacc[r] += Lc[qw][r][lane];
        float lsum = Oacc[8] + Lc[qw][8][lane];
        u32x2 lb = __builtin_amdgcn_permlane32_swap(__float_as_uint(lsum),
                                                    __float_as_uint(lsum), false, false);
        float inv = frcp(__uint_as_float(lb[0]));
        if (qtok < HW) {
            short* An = (short*)A + ((size_t)n * HW + qtok) * CH + head * 16;
            int2 pk0 = pack4(Oacc[0] * inv, Oacc[1] * inv, Oacc[2] * inv, Oacc[3] * inv);
            int2 pk1 = pack4(Oacc[4] * inv, Oacc[5] * inv, Oacc[6] * inv, Oacc[7] * inv);
            *(int2*)&An[hi * 4] = pk0;
            *(int2*)&An[8 + hi * 4] = pk1;
        }
    }
}

extern "C" void kernel_launch(void* const* d_in, const int* in_sizes, int n_in,
                              void* d_out, int out_size, void* d_ws, size_t ws_size,
                              hipStream_t stream) {
    char* ws = (char*)d_ws;
    bf16*  Wst  = (bf16*)(ws + 256);          // 327680 bf16
    float* Bst  = (float*)(ws + 655616);      // 768 f32
    bf16*  XT   = (bf16*)(ws + 1048576);      // channel-last [n][1296][128]
    bf16*  Zb   = XT + TT;
    bf16*  Qb   = Zb + TT;                    // head-grouped [n][8][1296][16]
    bf16*  Kb   = Qb + TT;
    bf16*  Vb   = Kb + TT;                    // channel-first [n][128][1296]
    bf16*  Ab   = Vb + TT;                    // ~17 MB total

    k_prep<<<1284, 256, 0, stream>>>(d_in[1], d_in[3], d_in[5], d_in[6], d_in[7],
                                     d_in[8], d_in[12], d_in[14], d_in[16],
                                     d_in[2], d_in[4], d_in[9], d_in[13], d_in[15], d_in[17],
                                     Wst, Bst);
    // n on blockIdx.x (gridDim.x == 8): linear wg id % 8 == n -> per-batch XCD locality
    k_inm<<<dim3(8, 41, 4), 256, 0, stream>>>(d_in[0], d_in[1], Wst, Bst, XT);
    k_cq<<<dim3(8, 41), 512, 0, stream>>>(XT, Wst + 16384, Bst + 128, Wst + 163840,
                                          Zb, Qb, Kb, Vb);
    k_attn<<<dim3(8, 11, 8), 512, 0, stream>>>(Qb, Kb, Vb, Ab);
    k_cell<<<dim3(8, 81), 256, 0, stream>>>(Zb, Ab, Wst + 212992, Bst + 256,
                                            Wst + 311296, Bst + 640, d_out, d_in[1]);
}